// Round 8
// baseline (220.151 us; speedup 1.0000x reference)
//
#include <hip/hip_runtime.h>

#define NN 50000
#define NE 800000
#define NBD3 391                    // ceil(NN/128) dense3 blocks
#define NBG 782                     // ceil(NN/64) fused gather+gemm blocks
#define PMAX (NBG*128)              // offset of max-partials in part buffer
#define NRED 64                     // reduced partial rows after k_attn_pre

// ---- counting-sort CSR build params ----
#define EC 4096                     // edges per chunk block
#define NBLKC 196                   // ceil(NE/EC)
#define NBUCK 1563                  // ceil(NN/32), 32 nodes per bucket
#define LT (NBUCK*NBLKC)            // hist entries = 306348
#define NS1 300                     // ceil(LT/1024) scan blocks
#define DCAP 1024                   // LDS staging cap in k_dsort

typedef __attribute__((ext_vector_type(8))) short bf16x8;
typedef __attribute__((ext_vector_type(4))) float f32x4;

__device__ __forceinline__ float elu_f(float x){ return x > 0.f ? x : __expf(x) - 1.f; }

__device__ __forceinline__ ushort f2bf(float f){
    unsigned u = __float_as_uint(f);
    unsigned r = (u + 0x7FFFu + ((u >> 16) & 1u)) >> 16;
    return (ushort)r;
}
__device__ __forceinline__ float bf2f(short u){
    return __uint_as_float(((unsigned)(unsigned short)u) << 16);
}

// ======== Pass A: per-chunk bucket histogram ========
__global__ __launch_bounds__(256) void k_bhist(const int* __restrict__ col, int* __restrict__ hist){
    __shared__ int h[NBUCK];
    int blk = blockIdx.x;
    for (int i = threadIdx.x; i < NBUCK; i += 256) h[i] = 0;
    __syncthreads();
    int base = blk * EC;
    #pragma unroll
    for (int i = 0; i < 16; ++i){
        int e = base + i*256 + threadIdx.x;
        if (e < NE) atomicAdd(&h[col[e] >> 5], 1);
    }
    __syncthreads();
    for (int i = threadIdx.x; i < NBUCK; i += 256) hist[i*NBLKC + blk] = h[i];
}

// ======== scan phase 1: 1024-chunk partial sums ========
__global__ __launch_bounds__(256) void k_s1(const int* __restrict__ hist, int* __restrict__ bsum){
    __shared__ int red[256];
    int base = blockIdx.x*1024 + threadIdx.x;
    int s = 0;
    #pragma unroll
    for (int i = 0; i < 4; ++i){ int idx = base + i*256; if (idx < LT) s += hist[idx]; }
    red[threadIdx.x] = s;
    __syncthreads();
    for (int off = 128; off > 0; off >>= 1){
        if (threadIdx.x < off) red[threadIdx.x] += red[threadIdx.x + off];
        __syncthreads();
    }
    if (threadIdx.x == 0) bsum[blockIdx.x] = red[0];
}

// ======== scan phase 2: scan NS1 partials ========
__global__ __launch_bounds__(512) void k_s2(const int* __restrict__ bsum, int* __restrict__ boff){
    __shared__ int s[512];
    int t = threadIdx.x;
    int v = (t < NS1) ? bsum[t] : 0;
    s[t] = v;
    __syncthreads();
    for (int off = 1; off < 512; off <<= 1){
        int u = (t >= off) ? s[t - off] : 0;
        __syncthreads();
        s[t] += u;
        __syncthreads();
    }
    if (t < NS1) boff[t] = s[t] - v;
}

// ======== scan phase 3: local scan + base -> scanned offsets + bucketPtr ========
__global__ __launch_bounds__(256) void k_s3(const int* __restrict__ hist, const int* __restrict__ boff,
                                            int* __restrict__ scanned, int* __restrict__ bucketPtr){
    __shared__ int red[256];
    int blk = blockIdx.x, t = threadIdx.x;
    int base = blk*1024;
    int v[4]; int s = 0;
    #pragma unroll
    for (int i = 0; i < 4; ++i){
        int idx = base + t*4 + i;
        v[i] = (idx < LT) ? hist[idx] : 0;
        s += v[i];
    }
    red[t] = s;
    __syncthreads();
    for (int off = 1; off < 256; off <<= 1){
        int u = (t >= off) ? red[t - off] : 0;
        __syncthreads();
        red[t] += u;
        __syncthreads();
    }
    int run = boff[blk] + red[t] - s;
    #pragma unroll
    for (int i = 0; i < 4; ++i){
        int idx = base + t*4 + i;
        if (idx < LT){
            scanned[idx] = run;
            if (idx % NBLKC == 0) bucketPtr[idx / NBLKC] = run;
            run += v[i];
        }
    }
    if (blk == 0 && t == 0) bucketPtr[NBUCK] = NE;
}

// ======== Pass C: bucket-sort edges (LDS cursors, no global atomics) ========
__global__ __launch_bounds__(256) void k_csort(const int* __restrict__ row, const int* __restrict__ col,
                                               const int* __restrict__ scanned, int2* __restrict__ edgeS){
    __shared__ int curs[NBUCK];
    int blk = blockIdx.x;
    for (int i = threadIdx.x; i < NBUCK; i += 256) curs[i] = scanned[i*NBLKC + blk];
    __syncthreads();
    int base = blk * EC;
    #pragma unroll
    for (int i = 0; i < 16; ++i){
        int e = base + i*256 + threadIdx.x;
        if (e < NE){
            int r = row[e], c = col[e];
            int pos = atomicAdd(&curs[c >> 5], 1);
            edgeS[pos] = make_int2(r, c);
        }
    }
}

// ======== Pass D: in-bucket per-node sort + nrm + rowptr ========
__global__ __launch_bounds__(256) void k_dsort(const float* __restrict__ dis, const int* __restrict__ bucketPtr,
                                               int2* __restrict__ edge, int* __restrict__ rowptr){
    __shared__ int nodeCnt[32];
    __shared__ int nodeOff[33];
    __shared__ float disL[32];
    __shared__ int2 stage[DCAP];
    int b = blockIdx.x, t = threadIdx.x;
    int j0 = bucketPtr[b], j1 = bucketPtr[b+1], cnt = j1 - j0;
    if (t < 32){
        nodeCnt[t] = 0;
        int c = b*32 + t;
        disL[t] = (c < NN) ? dis[c] : 0.f;
    }
    __syncthreads();
    int er[8], ec[8], rk[8]; int m = 0;
    for (int j = t; j < cnt && m < 8; j += 256){
        int2 e = edge[j0 + j];
        int cl = e.y & 31;
        er[m] = e.x; ec[m] = e.y;
        rk[m] = atomicAdd(&nodeCnt[cl], 1);
        ++m;
    }
    __syncthreads();
    if (t == 0){
        int run = 0;
        #pragma unroll
        for (int i = 0; i < 32; ++i){ nodeOff[i] = run; run += nodeCnt[i]; }
        nodeOff[32] = run;
    }
    __syncthreads();
    if (t < 32){
        int c = b*32 + t;
        if (c < NN) rowptr[c] = j0 + nodeOff[t];
    }
    if (b == 0 && t == 0) rowptr[NN] = NE;
    bool staged = (cnt <= DCAP);
    for (int i = 0; i < m; ++i){
        int r = er[i], cl = ec[i] & 31;
        float nm = dis[r] * disL[cl];
        int pos = nodeOff[cl] + rk[i];
        int2 rec = make_int2(r, __float_as_int(nm));
        if (staged) stage[pos] = rec;
        else        edge[j0 + pos] = rec;
    }
    __syncthreads();
    if (staged)
        for (int j = t; j < cnt; j += 256) edge[j0 + j] = stage[j];
}

// ======== layer 1: gather 3-channel, thread per node ========
__global__ void k_gather3(const float* __restrict__ x, const int* __restrict__ rowptr,
                          const int2* __restrict__ edge, float* __restrict__ agg){
    int n = blockIdx.x * blockDim.x + threadIdx.x;
    if (n >= NN) return;
    int j0 = rowptr[n], j1 = rowptr[n + 1];
    float a0 = 0.f, a1 = 0.f, a2 = 0.f;
    for (int j = j0; j < j1; ++j){
        int2 e = edge[j];
        int r = e.x; float w = __int_as_float(e.y);
        a0 = fmaf(x[r*3+0], w, a0);
        a1 = fmaf(x[r*3+1], w, a1);
        a2 = fmaf(x[r*3+2], w, a2);
    }
    agg[n*3+0] = a0; agg[n*3+1] = a1; agg[n*3+2] = a2;
}

// ---- layer 1 dense + fused pool (h stored bf16; pool in fp32 pre-round) ----
__global__ __launch_bounds__(128) void k_dense3p(const float* __restrict__ agg, const float* __restrict__ W,
                          const float* __restrict__ b, ushort* __restrict__ h, float* __restrict__ part){
    int c = threadIdx.x;
    int n0 = blockIdx.x * 128;
    int n1 = min(n0 + 128, NN);
    float w0 = W[c*3+0], w1 = W[c*3+1], w2 = W[c*3+2], bb = b[c];
    float s = 0.f, m = -3.4e38f;
    for (int n = n0; n < n1; ++n){
        float v = fmaf(agg[n*3+0], w0, fmaf(agg[n*3+1], w1, fmaf(agg[n*3+2], w2, bb)));
        v = elu_f(v);
        h[(size_t)n*128 + c] = f2bf(v);
        s += v; m = fmaxf(m, v);
    }
    part[blockIdx.x*128 + c] = s;
    part[PMAX + blockIdx.x*128 + c] = m;
}

// ---- pool partial pre-reduction ----
__global__ __launch_bounds__(256) void k_attn_pre(const float* __restrict__ part, int nblk,
                                                  float* __restrict__ part2){
    __shared__ float sS[2][128], sM[2][128];
    int c = threadIdx.x & 127, g = threadIdx.x >> 7;
    float s = 0.f, m = -3.4e38f;
    for (int b = blockIdx.x*2 + g; b < nblk; b += NRED*2){
        s += part[b*128 + c];
        m = fmaxf(m, part[PMAX + b*128 + c]);
    }
    sS[g][c] = s; sM[g][c] = m;
    __syncthreads();
    if (g == 0){
        part2[blockIdx.x*128 + c] = sS[0][c] + sS[1][c];
        part2[NRED*128 + blockIdx.x*128 + c] = fmaxf(sM[0][c], sM[1][c]);
    }
}

// ---- channel attention MLP + fold att into next weights ----
// mode 0: Wdst = bf16[16384] = bf16(Wsrc * diag(att))
// mode 1: Wdst = f32[384]   = Wsrc * diag(att)
__global__ __launch_bounds__(512) void k_attn(const float* __restrict__ part2,
                       const float* __restrict__ w1, const float* __restrict__ w2,
                       const float* __restrict__ Wsrc, void* __restrict__ Wdst, int mode){
    __shared__ float sAll[4][128], mAll[4][128];
    __shared__ float avg[128], mx[128], ha[8], hm[8], attL[128];
    int c = threadIdx.x & 127, g = threadIdx.x >> 7;
    float s = 0.f, m = -3.4e38f;
    #pragma unroll
    for (int b = 0; b < NRED/4; ++b){
        int r = b*4 + g;
        s += part2[r*128 + c];
        m = fmaxf(m, part2[NRED*128 + r*128 + c]);
    }
    sAll[g][c] = s; mAll[g][c] = m;
    __syncthreads();
    if (g == 0){
        s = sAll[0][c] + sAll[1][c] + sAll[2][c] + sAll[3][c];
        m = fmaxf(fmaxf(mAll[0][c], mAll[1][c]), fmaxf(mAll[2][c], mAll[3][c]));
        avg[c] = s / (float)NN;
        mx[c] = m;
    }
    __syncthreads();
    if (threadIdx.x < 8){
        int cc = threadIdx.x;
        float sa = 0.f, sm = 0.f;
        for (int k = 0; k < 128; ++k){
            float w = w1[cc*128 + k];
            sa += avg[k]*w; sm += mx[k]*w;
        }
        ha[cc] = fmaxf(sa, 0.f); hm[cc] = fmaxf(sm, 0.f);
    }
    __syncthreads();
    if (threadIdx.x < 128){
        float oa = 0.f, om = 0.f;
        for (int j = 0; j < 8; ++j){
            float w = w2[c*8 + j];
            oa += ha[j]*w; om += hm[j]*w;
        }
        attL[c] = 1.f / (1.f + __expf(-(oa + om)));
    }
    __syncthreads();
    if (mode == 0){
        ushort* wd = (ushort*)Wdst;
        for (int i = threadIdx.x; i < 16384; i += 512)
            wd[i] = f2bf(Wsrc[i] * attL[i & 127]);
    } else {
        float* wd = (float*)Wdst;
        if (threadIdx.x < 384)
            wd[threadIdx.x] = Wsrc[threadIdx.x] * attL[threadIdx.x & 127];
    }
}

// ======== fused gather + MFMA GEMM + pool: hout = ELU(gather(h)@Wb^T + b) ========
// h (input) and hout (output) are DISTINCT buffers (cross-block race otherwise).
__global__ __launch_bounds__(256) void k_gg(const ushort* __restrict__ h,
                        const int* __restrict__ rowptr, const int2* __restrict__ edge,
                        const ushort* __restrict__ Wb, const float* __restrict__ b,
                        ushort* __restrict__ hout, float* __restrict__ part){
    __shared__ ushort At[64*128];            // 16KB, XOR-swizzled 16B slots
    __shared__ float poolS[4][128], poolM[4][128];
    int tid = threadIdx.x;
    int n0b = blockIdx.x * 64;

    // ---- phase 1: gather, 4 lanes/node, 32 ch/lane ----
    {
        int node = tid >> 2;                 // 0..63
        int q = tid & 3;                     // channel quarter
        int n = n0b + node;
        float acc[32];
        #pragma unroll
        for (int i = 0; i < 32; ++i) acc[i] = 0.f;
        if (n < NN){
            int j0 = rowptr[n], j1 = rowptr[n + 1];
            const ushort* hq = h + q*32;
            int j = j0;
            for (; j + 1 < j1; j += 2){
                int2 e0 = edge[j], e1 = edge[j+1];
                const ushort* r0 = hq + (size_t)e0.x*128;
                const ushort* r1 = hq + (size_t)e1.x*128;
                bf16x8 v00 = *(const bf16x8*)(r0);
                bf16x8 v01 = *(const bf16x8*)(r0 + 8);
                bf16x8 v02 = *(const bf16x8*)(r0 + 16);
                bf16x8 v03 = *(const bf16x8*)(r0 + 24);
                bf16x8 v10 = *(const bf16x8*)(r1);
                bf16x8 v11 = *(const bf16x8*)(r1 + 8);
                bf16x8 v12 = *(const bf16x8*)(r1 + 16);
                bf16x8 v13 = *(const bf16x8*)(r1 + 24);
                float w0 = __int_as_float(e0.y), w1 = __int_as_float(e1.y);
                #pragma unroll
                for (int cc = 0; cc < 8; ++cc){
                    acc[cc]    = fmaf(bf2f(v00[cc]), w0, acc[cc]);
                    acc[8+cc]  = fmaf(bf2f(v01[cc]), w0, acc[8+cc]);
                    acc[16+cc] = fmaf(bf2f(v02[cc]), w0, acc[16+cc]);
                    acc[24+cc] = fmaf(bf2f(v03[cc]), w0, acc[24+cc]);
                    acc[cc]    = fmaf(bf2f(v10[cc]), w1, acc[cc]);
                    acc[8+cc]  = fmaf(bf2f(v11[cc]), w1, acc[8+cc]);
                    acc[16+cc] = fmaf(bf2f(v12[cc]), w1, acc[16+cc]);
                    acc[24+cc] = fmaf(bf2f(v13[cc]), w1, acc[24+cc]);
                }
            }
            if (j < j1){
                int2 e0 = edge[j];
                const ushort* r0 = hq + (size_t)e0.x*128;
                bf16x8 v00 = *(const bf16x8*)(r0);
                bf16x8 v01 = *(const bf16x8*)(r0 + 8);
                bf16x8 v02 = *(const bf16x8*)(r0 + 16);
                bf16x8 v03 = *(const bf16x8*)(r0 + 24);
                float w0 = __int_as_float(e0.y);
                #pragma unroll
                for (int cc = 0; cc < 8; ++cc){
                    acc[cc]    = fmaf(bf2f(v00[cc]), w0, acc[cc]);
                    acc[8+cc]  = fmaf(bf2f(v01[cc]), w0, acc[8+cc]);
                    acc[16+cc] = fmaf(bf2f(v02[cc]), w0, acc[16+cc]);
                    acc[24+cc] = fmaf(bf2f(v03[cc]), w0, acc[24+cc]);
                }
            }
        }
        #pragma unroll
        for (int k = 0; k < 4; ++k){
            bf16x8 o;
            #pragma unroll
            for (int cc = 0; cc < 8; ++cc) o[cc] = (short)f2bf(acc[k*8 + cc]);
            int s = q*4 + k;
            *(bf16x8*)((char*)At + node*256 + ((s ^ (node & 7)) << 4)) = o;
        }
    }
    __syncthreads();

    // ---- phase 2: MFMA, 4 waves x 16 nodes ----
    int wave = tid >> 6, l = tid & 63;
    int lr = l & 15, lk = l >> 4;
    int r = wave*16 + lr;
    bf16x8 a[4];
    #pragma unroll
    for (int kb = 0; kb < 4; ++kb){
        int s = kb*4 + lk;
        a[kb] = *(const bf16x8*)((char*)At + r*256 + ((s ^ (r & 7)) << 4));
    }
    int n0 = n0b + wave*16;
    float s_part[8], m_part[8];
    const ushort* wbase = Wb + (size_t)lr * 128 + lk * 8;
    #pragma unroll
    for (int t = 0; t < 8; ++t){
        int j0 = t * 16;
        float bias = b[j0 + lr];
        f32x4 acc = {bias, bias, bias, bias};
        const ushort* wrow = wbase + (size_t)j0 * 128;
        #pragma unroll
        for (int kb = 0; kb < 4; ++kb){
            bf16x8 bf = *(const bf16x8*)(wrow + kb * 32);
            acc = __builtin_amdgcn_mfma_f32_16x16x32_bf16(a[kb], bf, acc, 0, 0, 0);
        }
        float s = 0.f, m = -3.4e38f;
        #pragma unroll
        for (int rr = 0; rr < 4; ++rr){
            int n = n0 + lk * 4 + rr;
            float v = elu_f(acc[rr]);
            if (n < NN){
                hout[(size_t)n * 128 + j0 + lr] = f2bf(v);
                s += v; m = fmaxf(m, v);
            }
        }
        s += __shfl_xor(s, 16); s += __shfl_xor(s, 32);
        m = fmaxf(m, __shfl_xor(m, 16)); m = fmaxf(m, __shfl_xor(m, 32));
        s_part[t] = s; m_part[t] = m;
    }
    if (lk == 0){
        #pragma unroll
        for (int t = 0; t < 8; ++t){
            poolS[wave][t * 16 + lr] = s_part[t];
            poolM[wave][t * 16 + lr] = m_part[t];
        }
    }
    __syncthreads();
    if (tid < 128){
        float S = poolS[0][tid] + poolS[1][tid] + poolS[2][tid] + poolS[3][tid];
        float M = fmaxf(fmaxf(poolM[0][tid], poolM[1][tid]), fmaxf(poolM[2][tid], poolM[3][tid]));
        part[blockIdx.x * 128 + tid] = S;
        part[PMAX + blockIdx.x * 128 + tid] = M;
    }
}

// ---- output head: thread per node, att pre-folded into WoS ----
__global__ __launch_bounds__(256) void k_out(const ushort* __restrict__ h,
                      const float* __restrict__ WoS, const float* __restrict__ bo,
                      float* __restrict__ out){
    int n = blockIdx.x * blockDim.x + threadIdx.x;
    if (n >= NN) return;
    float acc0 = bo[0], acc1 = bo[1], acc2 = bo[2];
    const bf16x8* hv = (const bf16x8*)(h + (size_t)n*128);
    #pragma unroll
    for (int i = 0; i < 16; ++i){
        bf16x8 v = hv[i];
        #pragma unroll
        for (int c = 0; c < 8; ++c){
            int cc = i*8 + c;
            float hv_f = bf2f(v[c]);
            acc0 = fmaf(hv_f, WoS[cc],        acc0);
            acc1 = fmaf(hv_f, WoS[128 + cc],  acc1);
            acc2 = fmaf(hv_f, WoS[256 + cc],  acc2);
        }
    }
    out[n*3+0] = acc0; out[n*3+1] = acc1; out[n*3+2] = acc2;
}

extern "C" void kernel_launch(void* const* d_in, const int* in_sizes, int n_in,
                              void* d_out, int out_size, void* d_ws, size_t ws_size,
                              hipStream_t stream) {
    const float* x    = (const float*)d_in[0];
    const int*   ei   = (const int*)d_in[1];
    const int*   row  = ei;
    const int*   col  = ei + NE;
    const float* dis  = (const float*)d_in[2];
    const float* W1   = (const float*)d_in[3];
    const float* b1   = (const float*)d_in[4];
    const float* W2   = (const float*)d_in[5];
    const float* b2   = (const float*)d_in[6];
    const float* W3   = (const float*)d_in[7];
    const float* b3   = (const float*)d_in[8];
    const float* ca1w1= (const float*)d_in[9];
    const float* ca1w2= (const float*)d_in[10];
    const float* ca2w1= (const float*)d_in[11];
    const float* ca2w2= (const float*)d_in[12];
    const float* ca3w1= (const float*)d_in[13];
    const float* ca3w2= (const float*)d_in[14];
    const float* Wout = (const float*)d_in[15];
    const float* bout = (const float*)d_in[16];
    float* out = (float*)d_out;

    ushort* hB    = (ushort*)d_ws;                        // [NN,128] bf16 (layer1 out, layer3 out)
    ushort* hC    = hB + (size_t)NN*128;                  // [NN,128] bf16 (layer2 out)
    float*  agg3  = (float*)(hC + (size_t)NN*128);        // [NN,3]
    float*  part  = agg3 + (size_t)NN*3;                  // 2*PMAX
    float*  part2 = part + (size_t)2*PMAX;                // 2*NRED*128
    ushort* Wb2   = (ushort*)(part2 + 2*NRED*128);        // bf16[16384], att1-scaled W2
    ushort* Wb3   = Wb2 + 16384;                          // bf16[16384], att2-scaled W3
    float*  WoutS = (float*)(Wb3 + 16384);                // f32[384], att3-scaled Wout
    int2*   edge  = (int2*)(WoutS + 384);                 // [NE]
    int*    rowptr= (int*)(edge + NE);                    // [NN+1]
    int*    hist  = rowptr + NN + 1;                      // [LT]
    int*    scanned = hist + LT;                          // [LT]
    int*    bucketPtr = scanned + LT;                     // [NBUCK+1]
    int*    bsum  = bucketPtr + NBUCK + 1;                // [NS1]
    int*    boff  = bsum + NS1;                           // [NS1]

    // ---- CSR build: atomic-free two-level counting sort ----
    k_bhist<<<NBLKC, 256, 0, stream>>>(col, hist);
    k_s1<<<NS1, 256, 0, stream>>>(hist, bsum);
    k_s2<<<1, 512, 0, stream>>>(bsum, boff);
    k_s3<<<NS1, 256, 0, stream>>>(hist, boff, scanned, bucketPtr);
    k_csort<<<NBLKC, 256, 0, stream>>>(row, col, scanned, edge);
    k_dsort<<<NBUCK, 256, 0, stream>>>(dis, bucketPtr, edge, rowptr);

    // ---- layer 1 ----
    k_gather3<<<(NN+255)/256, 256, 0, stream>>>(x, rowptr, edge, agg3);
    k_dense3p<<<NBD3, 128, 0, stream>>>(agg3, W1, b1, hB, part);
    k_attn_pre<<<NRED, 256, 0, stream>>>(part, NBD3, part2);
    k_attn<<<1, 512, 0, stream>>>(part2, ca1w1, ca1w2, W2, (void*)Wb2, 0);

    // ---- layer 2 (fused gather+gemm): hB -> hC ----
    k_gg<<<NBG, 256, 0, stream>>>(hB, rowptr, edge, Wb2, b2, hC, part);
    k_attn_pre<<<NRED, 256, 0, stream>>>(part, NBG, part2);
    k_attn<<<1, 512, 0, stream>>>(part2, ca2w1, ca2w2, W3, (void*)Wb3, 0);

    // ---- layer 3 (fused gather+gemm): hC -> hB ----
    k_gg<<<NBG, 256, 0, stream>>>(hC, rowptr, edge, Wb3, b3, hB, part);
    k_attn_pre<<<NRED, 256, 0, stream>>>(part, NBG, part2);
    k_attn<<<1, 512, 0, stream>>>(part2, ca3w1, ca3w2, Wout, (void*)WoutS, 1);

    // ---- output head ----
    k_out<<<(NN+255)/256, 256, 0, stream>>>(hB, WoutS, bout, out);
}

// Round 9
// 217.202 us; speedup vs baseline: 1.0136x; 1.0136x over previous
//
#include <hip/hip_runtime.h>

#define NN 50000
#define NE 800000
#define NBD3 391                    // ceil(NN/128) dense3 blocks
#define NBG 782                     // ceil(NN/64) fused gather+gemm blocks
#define PMAX (NBG*128)              // offset of max-partials in part buffer
#define NRED 64                     // reduced partial rows after k_attn_pre

// ---- counting-sort CSR build params ----
#define EC 4096                     // edges per chunk block
#define NBLKC 196                   // ceil(NE/EC)
#define NBUCK 1563                  // ceil(NN/32), 32 nodes per bucket
#define LT (NBUCK*NBLKC)            // hist entries = 306348
#define NS1 300                     // ceil(LT/1024) scan blocks
#define DCAP 1024                   // LDS staging cap in k_dsort

typedef __attribute__((ext_vector_type(8))) short bf16x8;
typedef __attribute__((ext_vector_type(4))) float f32x4;

__device__ __forceinline__ float elu_f(float x){ return x > 0.f ? x : __expf(x) - 1.f; }

__device__ __forceinline__ ushort f2bf(float f){
    unsigned u = __float_as_uint(f);
    unsigned r = (u + 0x7FFFu + ((u >> 16) & 1u)) >> 16;
    return (ushort)r;
}
__device__ __forceinline__ float bf2f(short u){
    return __uint_as_float(((unsigned)(unsigned short)u) << 16);
}

// ======== Pass A: per-chunk bucket histogram ========
__global__ __launch_bounds__(256) void k_bhist(const int* __restrict__ col, int* __restrict__ hist){
    __shared__ int h[NBUCK];
    int blk = blockIdx.x;
    for (int i = threadIdx.x; i < NBUCK; i += 256) h[i] = 0;
    __syncthreads();
    int base = blk * EC;
    #pragma unroll
    for (int i = 0; i < 16; ++i){
        int e = base + i*256 + threadIdx.x;
        if (e < NE) atomicAdd(&h[col[e] >> 5], 1);
    }
    __syncthreads();
    for (int i = threadIdx.x; i < NBUCK; i += 256) hist[i*NBLKC + blk] = h[i];
}

// ======== scan phase 1: 1024-chunk partial sums ========
__global__ __launch_bounds__(256) void k_s1(const int* __restrict__ hist, int* __restrict__ bsum){
    __shared__ int red[256];
    int base = blockIdx.x*1024 + threadIdx.x;
    int s = 0;
    #pragma unroll
    for (int i = 0; i < 4; ++i){ int idx = base + i*256; if (idx < LT) s += hist[idx]; }
    red[threadIdx.x] = s;
    __syncthreads();
    for (int off = 128; off > 0; off >>= 1){
        if (threadIdx.x < off) red[threadIdx.x] += red[threadIdx.x + off];
        __syncthreads();
    }
    if (threadIdx.x == 0) bsum[blockIdx.x] = red[0];
}

// ======== scan phase 2: scan NS1 partials ========
__global__ __launch_bounds__(512) void k_s2(const int* __restrict__ bsum, int* __restrict__ boff){
    __shared__ int s[512];
    int t = threadIdx.x;
    int v = (t < NS1) ? bsum[t] : 0;
    s[t] = v;
    __syncthreads();
    for (int off = 1; off < 512; off <<= 1){
        int u = (t >= off) ? s[t - off] : 0;
        __syncthreads();
        s[t] += u;
        __syncthreads();
    }
    if (t < NS1) boff[t] = s[t] - v;
}

// ======== scan phase 3: local scan + base -> scanned offsets + bucketPtr ========
__global__ __launch_bounds__(256) void k_s3(const int* __restrict__ hist, const int* __restrict__ boff,
                                            int* __restrict__ scanned, int* __restrict__ bucketPtr){
    __shared__ int red[256];
    int blk = blockIdx.x, t = threadIdx.x;
    int base = blk*1024;
    int v[4]; int s = 0;
    #pragma unroll
    for (int i = 0; i < 4; ++i){
        int idx = base + t*4 + i;
        v[i] = (idx < LT) ? hist[idx] : 0;
        s += v[i];
    }
    red[t] = s;
    __syncthreads();
    for (int off = 1; off < 256; off <<= 1){
        int u = (t >= off) ? red[t - off] : 0;
        __syncthreads();
        red[t] += u;
        __syncthreads();
    }
    int run = boff[blk] + red[t] - s;
    #pragma unroll
    for (int i = 0; i < 4; ++i){
        int idx = base + t*4 + i;
        if (idx < LT){
            scanned[idx] = run;
            if (idx % NBLKC == 0) bucketPtr[idx / NBLKC] = run;
            run += v[i];
        }
    }
    if (blk == 0 && t == 0) bucketPtr[NBUCK] = NE;
}

// ======== Pass C: bucket-sort edges (LDS cursors, no global atomics) ========
__global__ __launch_bounds__(256) void k_csort(const int* __restrict__ row, const int* __restrict__ col,
                                               const int* __restrict__ scanned, int2* __restrict__ edgeS){
    __shared__ int curs[NBUCK];
    int blk = blockIdx.x;
    for (int i = threadIdx.x; i < NBUCK; i += 256) curs[i] = scanned[i*NBLKC + blk];
    __syncthreads();
    int base = blk * EC;
    #pragma unroll
    for (int i = 0; i < 16; ++i){
        int e = base + i*256 + threadIdx.x;
        if (e < NE){
            int r = row[e], c = col[e];
            int pos = atomicAdd(&curs[c >> 5], 1);
            edgeS[pos] = make_int2(r, c);
        }
    }
}

// ======== Pass D: in-bucket per-node sort + nrm + rowptr ========
__global__ __launch_bounds__(256) void k_dsort(const float* __restrict__ dis, const int* __restrict__ bucketPtr,
                                               int2* __restrict__ edge, int* __restrict__ rowptr){
    __shared__ int nodeCnt[32];
    __shared__ int nodeOff[33];
    __shared__ float disL[32];
    __shared__ int2 stage[DCAP];
    int b = blockIdx.x, t = threadIdx.x;
    int j0 = bucketPtr[b], j1 = bucketPtr[b+1], cnt = j1 - j0;
    if (t < 32){
        nodeCnt[t] = 0;
        int c = b*32 + t;
        disL[t] = (c < NN) ? dis[c] : 0.f;
    }
    __syncthreads();
    int er[8], ec[8], rk[8]; int m = 0;
    for (int j = t; j < cnt && m < 8; j += 256){
        int2 e = edge[j0 + j];
        int cl = e.y & 31;
        er[m] = e.x; ec[m] = e.y;
        rk[m] = atomicAdd(&nodeCnt[cl], 1);
        ++m;
    }
    __syncthreads();
    if (t == 0){
        int run = 0;
        #pragma unroll
        for (int i = 0; i < 32; ++i){ nodeOff[i] = run; run += nodeCnt[i]; }
        nodeOff[32] = run;
    }
    __syncthreads();
    if (t < 32){
        int c = b*32 + t;
        if (c < NN) rowptr[c] = j0 + nodeOff[t];
    }
    if (b == 0 && t == 0) rowptr[NN] = NE;
    bool staged = (cnt <= DCAP);
    for (int i = 0; i < m; ++i){
        int r = er[i], cl = ec[i] & 31;
        float nm = dis[r] * disL[cl];
        int pos = nodeOff[cl] + rk[i];
        int2 rec = make_int2(r, __float_as_int(nm));
        if (staged) stage[pos] = rec;
        else        edge[j0 + pos] = rec;
    }
    __syncthreads();
    if (staged)
        for (int j = t; j < cnt; j += 256) edge[j0 + j] = stage[j];
}

// ======== layer 1: gather 3-channel, thread per node ========
__global__ void k_gather3(const float* __restrict__ x, const int* __restrict__ rowptr,
                          const int2* __restrict__ edge, float* __restrict__ agg){
    int n = blockIdx.x * blockDim.x + threadIdx.x;
    if (n >= NN) return;
    int j0 = rowptr[n], j1 = rowptr[n + 1];
    float a0 = 0.f, a1 = 0.f, a2 = 0.f;
    for (int j = j0; j < j1; ++j){
        int2 e = edge[j];
        int r = e.x; float w = __int_as_float(e.y);
        a0 = fmaf(x[r*3+0], w, a0);
        a1 = fmaf(x[r*3+1], w, a1);
        a2 = fmaf(x[r*3+2], w, a2);
    }
    agg[n*3+0] = a0; agg[n*3+1] = a1; agg[n*3+2] = a2;
}

// ---- layer 1 dense + fused pool (h stored bf16; pool in fp32 pre-round) ----
__global__ __launch_bounds__(128) void k_dense3p(const float* __restrict__ agg, const float* __restrict__ W,
                          const float* __restrict__ b, ushort* __restrict__ h, float* __restrict__ part){
    int c = threadIdx.x;
    int n0 = blockIdx.x * 128;
    int n1 = min(n0 + 128, NN);
    float w0 = W[c*3+0], w1 = W[c*3+1], w2 = W[c*3+2], bb = b[c];
    float s = 0.f, m = -3.4e38f;
    for (int n = n0; n < n1; ++n){
        float v = fmaf(agg[n*3+0], w0, fmaf(agg[n*3+1], w1, fmaf(agg[n*3+2], w2, bb)));
        v = elu_f(v);
        h[(size_t)n*128 + c] = f2bf(v);
        s += v; m = fmaxf(m, v);
    }
    part[blockIdx.x*128 + c] = s;
    part[PMAX + blockIdx.x*128 + c] = m;
}

// ---- pool partial pre-reduction ----
__global__ __launch_bounds__(256) void k_attn_pre(const float* __restrict__ part, int nblk,
                                                  float* __restrict__ part2){
    __shared__ float sS[2][128], sM[2][128];
    int c = threadIdx.x & 127, g = threadIdx.x >> 7;
    float s = 0.f, m = -3.4e38f;
    for (int b = blockIdx.x*2 + g; b < nblk; b += NRED*2){
        s += part[b*128 + c];
        m = fmaxf(m, part[PMAX + b*128 + c]);
    }
    sS[g][c] = s; sM[g][c] = m;
    __syncthreads();
    if (g == 0){
        part2[blockIdx.x*128 + c] = sS[0][c] + sS[1][c];
        part2[NRED*128 + blockIdx.x*128 + c] = fmaxf(sM[0][c], sM[1][c]);
    }
}

// ---- channel attention MLP + fold att into next weights ----
// mode 0: Wdst = bf16[16384] = bf16(Wsrc * diag(att))
// mode 1: Wdst = f32[384]   = Wsrc * diag(att)
__global__ __launch_bounds__(512) void k_attn(const float* __restrict__ part2,
                       const float* __restrict__ w1, const float* __restrict__ w2,
                       const float* __restrict__ Wsrc, void* __restrict__ Wdst, int mode){
    __shared__ float sAll[4][128], mAll[4][128];
    __shared__ float avg[128], mx[128], ha[8], hm[8], attL[128];
    int c = threadIdx.x & 127, g = threadIdx.x >> 7;
    float s = 0.f, m = -3.4e38f;
    #pragma unroll
    for (int b = 0; b < NRED/4; ++b){
        int r = b*4 + g;
        s += part2[r*128 + c];
        m = fmaxf(m, part2[NRED*128 + r*128 + c]);
    }
    sAll[g][c] = s; mAll[g][c] = m;
    __syncthreads();
    if (g == 0){
        s = sAll[0][c] + sAll[1][c] + sAll[2][c] + sAll[3][c];
        m = fmaxf(fmaxf(mAll[0][c], mAll[1][c]), fmaxf(mAll[2][c], mAll[3][c]));
        avg[c] = s / (float)NN;
        mx[c] = m;
    }
    __syncthreads();
    if (threadIdx.x < 8){
        int cc = threadIdx.x;
        float sa = 0.f, sm = 0.f;
        for (int k = 0; k < 128; ++k){
            float w = w1[cc*128 + k];
            sa += avg[k]*w; sm += mx[k]*w;
        }
        ha[cc] = fmaxf(sa, 0.f); hm[cc] = fmaxf(sm, 0.f);
    }
    __syncthreads();
    if (threadIdx.x < 128){
        float oa = 0.f, om = 0.f;
        for (int j = 0; j < 8; ++j){
            float w = w2[c*8 + j];
            oa += ha[j]*w; om += hm[j]*w;
        }
        attL[c] = 1.f / (1.f + __expf(-(oa + om)));
    }
    __syncthreads();
    if (mode == 0){
        ushort* wd = (ushort*)Wdst;
        for (int i = threadIdx.x; i < 16384; i += 512)
            wd[i] = f2bf(Wsrc[i] * attL[i & 127]);
    } else {
        float* wd = (float*)Wdst;
        if (threadIdx.x < 384)
            wd[threadIdx.x] = Wsrc[threadIdx.x] * attL[threadIdx.x & 127];
    }
}

// ======== fused gather + MFMA GEMM + pool, 512 threads / 64 nodes ========
// Phase 1: gather, 8 lanes/node, 16 ch/lane, unroll-4 (8 outstanding 32B loads)
// Phase 2: 8 waves; wave w: node-tile (w>>1), column-half (w&1); MFMA 16x16x32
// h (input) and hout (output) are DISTINCT buffers (cross-block race otherwise).
__global__ __launch_bounds__(512) void k_gg(const ushort* __restrict__ h,
                        const int* __restrict__ rowptr, const int2* __restrict__ edge,
                        const ushort* __restrict__ Wb, const float* __restrict__ b,
                        ushort* __restrict__ hout, float* __restrict__ part){
    __shared__ ushort At[64*128];            // 16KB, XOR-swizzled 16B slots
    __shared__ float poolS[8][64], poolM[8][64];
    int tid = threadIdx.x;
    int n0b = blockIdx.x * 64;

    // ---- phase 1: gather ----
    {
        int node = tid >> 3;                 // 0..63
        int l8 = tid & 7;                    // channel sixteenth-pair
        int n = n0b + node;
        float acc[16];
        #pragma unroll
        for (int i = 0; i < 16; ++i) acc[i] = 0.f;
        if (n < NN){
            int j0 = rowptr[n], j1 = rowptr[n + 1];
            const ushort* hq = h + l8*16;
            int j = j0;
            for (; j + 3 < j1; j += 4){
                int2 e0 = edge[j], e1 = edge[j+1], e2 = edge[j+2], e3 = edge[j+3];
                const ushort* r0 = hq + (size_t)e0.x*128;
                const ushort* r1 = hq + (size_t)e1.x*128;
                const ushort* r2 = hq + (size_t)e2.x*128;
                const ushort* r3 = hq + (size_t)e3.x*128;
                bf16x8 v0a = *(const bf16x8*)(r0), v0b = *(const bf16x8*)(r0 + 8);
                bf16x8 v1a = *(const bf16x8*)(r1), v1b = *(const bf16x8*)(r1 + 8);
                bf16x8 v2a = *(const bf16x8*)(r2), v2b = *(const bf16x8*)(r2 + 8);
                bf16x8 v3a = *(const bf16x8*)(r3), v3b = *(const bf16x8*)(r3 + 8);
                float w0 = __int_as_float(e0.y), w1 = __int_as_float(e1.y);
                float w2 = __int_as_float(e2.y), w3 = __int_as_float(e3.y);
                #pragma unroll
                for (int cc = 0; cc < 8; ++cc){
                    acc[cc]   = fmaf(bf2f(v0a[cc]), w0, acc[cc]);
                    acc[8+cc] = fmaf(bf2f(v0b[cc]), w0, acc[8+cc]);
                    acc[cc]   = fmaf(bf2f(v1a[cc]), w1, acc[cc]);
                    acc[8+cc] = fmaf(bf2f(v1b[cc]), w1, acc[8+cc]);
                    acc[cc]   = fmaf(bf2f(v2a[cc]), w2, acc[cc]);
                    acc[8+cc] = fmaf(bf2f(v2b[cc]), w2, acc[8+cc]);
                    acc[cc]   = fmaf(bf2f(v3a[cc]), w3, acc[cc]);
                    acc[8+cc] = fmaf(bf2f(v3b[cc]), w3, acc[8+cc]);
                }
            }
            for (; j < j1; ++j){
                int2 e0 = edge[j];
                const ushort* r0 = hq + (size_t)e0.x*128;
                bf16x8 v0a = *(const bf16x8*)(r0), v0b = *(const bf16x8*)(r0 + 8);
                float w0 = __int_as_float(e0.y);
                #pragma unroll
                for (int cc = 0; cc < 8; ++cc){
                    acc[cc]   = fmaf(bf2f(v0a[cc]), w0, acc[cc]);
                    acc[8+cc] = fmaf(bf2f(v0b[cc]), w0, acc[8+cc]);
                }
            }
        }
        #pragma unroll
        for (int k = 0; k < 2; ++k){
            bf16x8 o;
            #pragma unroll
            for (int cc = 0; cc < 8; ++cc) o[cc] = (short)f2bf(acc[k*8 + cc]);
            int s = l8*2 + k;
            *(bf16x8*)((char*)At + node*256 + ((s ^ (node & 7)) << 4)) = o;
        }
    }
    __syncthreads();

    // ---- phase 2: MFMA, wave w -> node-tile (w>>1) x column-half (w&1) ----
    int wave = tid >> 6, l = tid & 63;
    int nt = wave >> 1, jh = wave & 1;
    int lr = l & 15, lk = l >> 4;
    int r = nt*16 + lr;
    bf16x8 a[4];
    #pragma unroll
    for (int kb = 0; kb < 4; ++kb){
        int s = kb*4 + lk;
        a[kb] = *(const bf16x8*)((char*)At + r*256 + ((s ^ (r & 7)) << 4));
    }
    int n0 = n0b + nt*16;
    float s_part[4], m_part[4];
    const ushort* wbase = Wb + (size_t)lr * 128 + lk * 8;
    #pragma unroll
    for (int t = 0; t < 4; ++t){
        int j0 = jh*64 + t*16;
        float bias = b[j0 + lr];
        f32x4 acc = {bias, bias, bias, bias};
        const ushort* wrow = wbase + (size_t)j0 * 128;
        #pragma unroll
        for (int kb = 0; kb < 4; ++kb){
            bf16x8 bf = *(const bf16x8*)(wrow + kb * 32);
            acc = __builtin_amdgcn_mfma_f32_16x16x32_bf16(a[kb], bf, acc, 0, 0, 0);
        }
        float s = 0.f, m = -3.4e38f;
        #pragma unroll
        for (int rr = 0; rr < 4; ++rr){
            int n = n0 + lk * 4 + rr;
            float v = elu_f(acc[rr]);
            if (n < NN){
                hout[(size_t)n * 128 + j0 + lr] = f2bf(v);
                s += v; m = fmaxf(m, v);
            }
        }
        s += __shfl_xor(s, 16); s += __shfl_xor(s, 32);
        m = fmaxf(m, __shfl_xor(m, 16)); m = fmaxf(m, __shfl_xor(m, 32));
        s_part[t] = s; m_part[t] = m;
    }
    if (lk == 0){
        #pragma unroll
        for (int t = 0; t < 4; ++t){
            poolS[wave][t * 16 + lr] = s_part[t];
            poolM[wave][t * 16 + lr] = m_part[t];
        }
    }
    __syncthreads();
    if (tid < 128){
        int c = tid, j2 = c >> 6, lc = c & 63;
        float S = poolS[0 + j2][lc] + poolS[2 + j2][lc] + poolS[4 + j2][lc] + poolS[6 + j2][lc];
        float M = fmaxf(fmaxf(poolM[0 + j2][lc], poolM[2 + j2][lc]),
                        fmaxf(poolM[4 + j2][lc], poolM[6 + j2][lc]));
        part[blockIdx.x * 128 + c] = S;
        part[PMAX + blockIdx.x * 128 + c] = M;
    }
}

// ---- output head: thread per node, att pre-folded into WoS ----
__global__ __launch_bounds__(256) void k_out(const ushort* __restrict__ h,
                      const float* __restrict__ WoS, const float* __restrict__ bo,
                      float* __restrict__ out){
    int n = blockIdx.x * blockDim.x + threadIdx.x;
    if (n >= NN) return;
    float acc0 = bo[0], acc1 = bo[1], acc2 = bo[2];
    const bf16x8* hv = (const bf16x8*)(h + (size_t)n*128);
    #pragma unroll
    for (int i = 0; i < 16; ++i){
        bf16x8 v = hv[i];
        #pragma unroll
        for (int c = 0; c < 8; ++c){
            int cc = i*8 + c;
            float hv_f = bf2f(v[c]);
            acc0 = fmaf(hv_f, WoS[cc],        acc0);
            acc1 = fmaf(hv_f, WoS[128 + cc],  acc1);
            acc2 = fmaf(hv_f, WoS[256 + cc],  acc2);
        }
    }
    out[n*3+0] = acc0; out[n*3+1] = acc1; out[n*3+2] = acc2;
}

extern "C" void kernel_launch(void* const* d_in, const int* in_sizes, int n_in,
                              void* d_out, int out_size, void* d_ws, size_t ws_size,
                              hipStream_t stream) {
    const float* x    = (const float*)d_in[0];
    const int*   ei   = (const int*)d_in[1];
    const int*   row  = ei;
    const int*   col  = ei + NE;
    const float* dis  = (const float*)d_in[2];
    const float* W1   = (const float*)d_in[3];
    const float* b1   = (const float*)d_in[4];
    const float* W2   = (const float*)d_in[5];
    const float* b2   = (const float*)d_in[6];
    const float* W3   = (const float*)d_in[7];
    const float* b3   = (const float*)d_in[8];
    const float* ca1w1= (const float*)d_in[9];
    const float* ca1w2= (const float*)d_in[10];
    const float* ca2w1= (const float*)d_in[11];
    const float* ca2w2= (const float*)d_in[12];
    const float* ca3w1= (const float*)d_in[13];
    const float* ca3w2= (const float*)d_in[14];
    const float* Wout = (const float*)d_in[15];
    const float* bout = (const float*)d_in[16];
    float* out = (float*)d_out;

    ushort* hB    = (ushort*)d_ws;                        // [NN,128] bf16 (layer1 out, layer3 out)
    ushort* hC    = hB + (size_t)NN*128;                  // [NN,128] bf16 (layer2 out)
    float*  agg3  = (float*)(hC + (size_t)NN*128);        // [NN,3]
    float*  part  = agg3 + (size_t)NN*3;                  // 2*PMAX
    float*  part2 = part + (size_t)2*PMAX;                // 2*NRED*128
    ushort* Wb2   = (ushort*)(part2 + 2*NRED*128);        // bf16[16384], att1-scaled W2
    ushort* Wb3   = Wb2 + 16384;                          // bf16[16384], att2-scaled W3
    float*  WoutS = (float*)(Wb3 + 16384);                // f32[384], att3-scaled Wout
    int2*   edge  = (int2*)(WoutS + 384);                 // [NE]
    int*    rowptr= (int*)(edge + NE);                    // [NN+1]
    int*    hist  = rowptr + NN + 1;                      // [LT]
    int*    scanned = hist + LT;                          // [LT]
    int*    bucketPtr = scanned + LT;                     // [NBUCK+1]
    int*    bsum  = bucketPtr + NBUCK + 1;                // [NS1]
    int*    boff  = bsum + NS1;                           // [NS1]

    // ---- CSR build: atomic-free two-level counting sort ----
    k_bhist<<<NBLKC, 256, 0, stream>>>(col, hist);
    k_s1<<<NS1, 256, 0, stream>>>(hist, bsum);
    k_s2<<<1, 512, 0, stream>>>(bsum, boff);
    k_s3<<<NS1, 256, 0, stream>>>(hist, boff, scanned, bucketPtr);
    k_csort<<<NBLKC, 256, 0, stream>>>(row, col, scanned, edge);
    k_dsort<<<NBUCK, 256, 0, stream>>>(dis, bucketPtr, edge, rowptr);

    // ---- layer 1 ----
    k_gather3<<<(NN+255)/256, 256, 0, stream>>>(x, rowptr, edge, agg3);
    k_dense3p<<<NBD3, 128, 0, stream>>>(agg3, W1, b1, hB, part);
    k_attn_pre<<<NRED, 256, 0, stream>>>(part, NBD3, part2);
    k_attn<<<1, 512, 0, stream>>>(part2, ca1w1, ca1w2, W2, (void*)Wb2, 0);

    // ---- layer 2 (fused gather+gemm): hB -> hC ----
    k_gg<<<NBG, 512, 0, stream>>>(hB, rowptr, edge, Wb2, b2, hC, part);
    k_attn_pre<<<NRED, 256, 0, stream>>>(part, NBG, part2);
    k_attn<<<1, 512, 0, stream>>>(part2, ca2w1, ca2w2, W3, (void*)Wb3, 0);

    // ---- layer 3 (fused gather+gemm): hC -> hB ----
    k_gg<<<NBG, 512, 0, stream>>>(hC, rowptr, edge, Wb3, b3, hB, part);
    k_attn_pre<<<NRED, 256, 0, stream>>>(part, NBG, part2);
    k_attn<<<1, 512, 0, stream>>>(part2, ca3w1, ca3w2, Wout, (void*)WoutS, 1);

    // ---- output head ----
    k_out<<<(NN+255)/256, 256, 0, stream>>>(hB, WoutS, bout, out);
}

// Round 10
// 210.702 us; speedup vs baseline: 1.0448x; 1.0309x over previous
//
#include <hip/hip_runtime.h>

#define NN 50000
#define NE 800000
#define NPAD 50176                  // NN padded to multiple of 64
#define NBD3 391                    // ceil(NN/128) layer-1 blocks
#define NBG 782                     // ceil(NN/64) mfma-gemm blocks
#define PMAX (NBG*128)              // offset of max-partials in part buffer
#define NRED 64                     // reduced partial rows after k_attn_pre

// ---- counting-sort CSR build params ----
#define EC 4096                     // edges per chunk block
#define NBLKC 196                   // ceil(NE/EC)
#define NBUCK 1563                  // ceil(NN/32), 32 nodes per bucket
#define LT (NBUCK*NBLKC)            // hist entries = 306348
#define NS1 300                     // ceil(LT/1024) scan blocks
#define DCAP 1024                   // LDS staging cap in k_dsort

typedef __attribute__((ext_vector_type(8))) short bf16x8;
typedef __attribute__((ext_vector_type(4))) float f32x4;

__device__ __forceinline__ float elu_f(float x){ return x > 0.f ? x : __expf(x) - 1.f; }

__device__ __forceinline__ ushort f2bf(float f){
    unsigned u = __float_as_uint(f);
    unsigned r = (u + 0x7FFFu + ((u >> 16) & 1u)) >> 16;
    return (ushort)r;
}
__device__ __forceinline__ float bf2f(short u){
    return __uint_as_float(((unsigned)(unsigned short)u) << 16);
}

// ======== Pass A: per-chunk bucket histogram ========
__global__ __launch_bounds__(256) void k_bhist(const int* __restrict__ col, int* __restrict__ hist){
    __shared__ int h[NBUCK];
    int blk = blockIdx.x;
    for (int i = threadIdx.x; i < NBUCK; i += 256) h[i] = 0;
    __syncthreads();
    int base = blk * EC;
    #pragma unroll
    for (int i = 0; i < 16; ++i){
        int e = base + i*256 + threadIdx.x;
        if (e < NE) atomicAdd(&h[col[e] >> 5], 1);
    }
    __syncthreads();
    for (int i = threadIdx.x; i < NBUCK; i += 256) hist[i*NBLKC + blk] = h[i];
}

// ======== scan phase 1: 1024-chunk partial sums ========
__global__ __launch_bounds__(256) void k_s1(const int* __restrict__ hist, int* __restrict__ bsum){
    __shared__ int red[256];
    int base = blockIdx.x*1024 + threadIdx.x;
    int s = 0;
    #pragma unroll
    for (int i = 0; i < 4; ++i){ int idx = base + i*256; if (idx < LT) s += hist[idx]; }
    red[threadIdx.x] = s;
    __syncthreads();
    for (int off = 128; off > 0; off >>= 1){
        if (threadIdx.x < off) red[threadIdx.x] += red[threadIdx.x + off];
        __syncthreads();
    }
    if (threadIdx.x == 0) bsum[blockIdx.x] = red[0];
}

// ======== scan phase 2: scan NS1 partials ========
__global__ __launch_bounds__(512) void k_s2(const int* __restrict__ bsum, int* __restrict__ boff){
    __shared__ int s[512];
    int t = threadIdx.x;
    int v = (t < NS1) ? bsum[t] : 0;
    s[t] = v;
    __syncthreads();
    for (int off = 1; off < 512; off <<= 1){
        int u = (t >= off) ? s[t - off] : 0;
        __syncthreads();
        s[t] += u;
        __syncthreads();
    }
    if (t < NS1) boff[t] = s[t] - v;
}

// ======== scan phase 3: local scan + base -> scanned offsets + bucketPtr ========
__global__ __launch_bounds__(256) void k_s3(const int* __restrict__ hist, const int* __restrict__ boff,
                                            int* __restrict__ scanned, int* __restrict__ bucketPtr){
    __shared__ int red[256];
    int blk = blockIdx.x, t = threadIdx.x;
    int base = blk*1024;
    int v[4]; int s = 0;
    #pragma unroll
    for (int i = 0; i < 4; ++i){
        int idx = base + t*4 + i;
        v[i] = (idx < LT) ? hist[idx] : 0;
        s += v[i];
    }
    red[t] = s;
    __syncthreads();
    for (int off = 1; off < 256; off <<= 1){
        int u = (t >= off) ? red[t - off] : 0;
        __syncthreads();
        red[t] += u;
        __syncthreads();
    }
    int run = boff[blk] + red[t] - s;
    #pragma unroll
    for (int i = 0; i < 4; ++i){
        int idx = base + t*4 + i;
        if (idx < LT){
            scanned[idx] = run;
            if (idx % NBLKC == 0) bucketPtr[idx / NBLKC] = run;
            run += v[i];
        }
    }
    if (blk == 0 && t == 0) bucketPtr[NBUCK] = NE;
}

// ======== Pass C: bucket-sort edges (LDS cursors, no global atomics) ========
__global__ __launch_bounds__(256) void k_csort(const int* __restrict__ row, const int* __restrict__ col,
                                               const int* __restrict__ scanned, int2* __restrict__ edgeS){
    __shared__ int curs[NBUCK];
    int blk = blockIdx.x;
    for (int i = threadIdx.x; i < NBUCK; i += 256) curs[i] = scanned[i*NBLKC + blk];
    __syncthreads();
    int base = blk * EC;
    #pragma unroll
    for (int i = 0; i < 16; ++i){
        int e = base + i*256 + threadIdx.x;
        if (e < NE){
            int r = row[e], c = col[e];
            int pos = atomicAdd(&curs[c >> 5], 1);
            edgeS[pos] = make_int2(r, c);
        }
    }
}

// ======== Pass D: in-bucket per-node sort + nrm + rowptr ========
__global__ __launch_bounds__(256) void k_dsort(const float* __restrict__ dis, const int* __restrict__ bucketPtr,
                                               int2* __restrict__ edge, int* __restrict__ rowptr){
    __shared__ int nodeCnt[32];
    __shared__ int nodeOff[33];
    __shared__ float disL[32];
    __shared__ int2 stage[DCAP];
    int b = blockIdx.x, t = threadIdx.x;
    int j0 = bucketPtr[b], j1 = bucketPtr[b+1], cnt = j1 - j0;
    if (t < 32){
        nodeCnt[t] = 0;
        int c = b*32 + t;
        disL[t] = (c < NN) ? dis[c] : 0.f;
    }
    __syncthreads();
    int er[8], ec[8], rk[8]; int m = 0;
    for (int j = t; j < cnt && m < 8; j += 256){
        int2 e = edge[j0 + j];
        int cl = e.y & 31;
        er[m] = e.x; ec[m] = e.y;
        rk[m] = atomicAdd(&nodeCnt[cl], 1);
        ++m;
    }
    __syncthreads();
    if (t == 0){
        int run = 0;
        #pragma unroll
        for (int i = 0; i < 32; ++i){ nodeOff[i] = run; run += nodeCnt[i]; }
        nodeOff[32] = run;
    }
    __syncthreads();
    if (t < 32){
        int c = b*32 + t;
        if (c < NN) rowptr[c] = j0 + nodeOff[t];
    }
    if (b == 0 && t == 0) rowptr[NN] = NE;
    bool staged = (cnt <= DCAP);
    for (int i = 0; i < m; ++i){
        int r = er[i], cl = ec[i] & 31;
        float nm = dis[r] * disL[cl];
        int pos = nodeOff[cl] + rk[i];
        int2 rec = make_int2(r, __float_as_int(nm));
        if (staged) stage[pos] = rec;
        else        edge[j0 + pos] = rec;
    }
    __syncthreads();
    if (staged)
        for (int j = t; j < cnt; j += 256) edge[j0 + j] = stage[j];
}

// ======== layer 1 fused: gather3 (thread/node) + dense128 (thread/channel) + pool ========
__global__ __launch_bounds__(128) void k_l1(const float* __restrict__ x, const int* __restrict__ rowptr,
                        const int2* __restrict__ edge, const float* __restrict__ W,
                        const float* __restrict__ b, ushort* __restrict__ h, float* __restrict__ part){
    __shared__ float aggL[128*3];
    int t = threadIdx.x;
    int n0 = blockIdx.x * 128;
    int nEnd = min(n0 + 128, NN);
    // phase 1: thread t gathers node n0+t
    {
        int n = n0 + t;
        float a0 = 0.f, a1 = 0.f, a2 = 0.f;
        if (n < NN){
            int j0 = rowptr[n], j1 = rowptr[n + 1];
            for (int j = j0; j < j1; ++j){
                int2 e = edge[j];
                int r = e.x; float w = __int_as_float(e.y);
                a0 = fmaf(x[r*3+0], w, a0);
                a1 = fmaf(x[r*3+1], w, a1);
                a2 = fmaf(x[r*3+2], w, a2);
            }
        }
        aggL[t*3+0] = a0; aggL[t*3+1] = a1; aggL[t*3+2] = a2;
    }
    __syncthreads();
    // phase 2: thread c computes channel c for nodes n0..nEnd
    int c = t;
    float w0 = W[c*3+0], w1 = W[c*3+1], w2 = W[c*3+2], bb = b[c];
    float s = 0.f, m = -3.4e38f;
    for (int n = n0; n < nEnd; ++n){
        int nn = n - n0;
        float v = fmaf(aggL[nn*3+0], w0, fmaf(aggL[nn*3+1], w1, fmaf(aggL[nn*3+2], w2, bb)));
        v = elu_f(v);
        h[(size_t)n*128 + c] = f2bf(v);
        s += v; m = fmaxf(m, v);
    }
    part[blockIdx.x*128 + c] = s;
    part[PMAX + blockIdx.x*128 + c] = m;
}

// ======== 128-channel gather (bf16 h): 16 lanes/node, 8 ch/lane ========
__global__ __launch_bounds__(256) void k_gather128(const ushort* __restrict__ h,
                              const int* __restrict__ rowptr, const int2* __restrict__ edge,
                              ushort* __restrict__ aggB){
    int t = blockIdx.x * blockDim.x + threadIdx.x;
    int n = t >> 4, l = t & 15;
    if (n >= NN) return;
    int j0 = rowptr[n], j1 = rowptr[n + 1];
    float acc[8] = {0.f,0.f,0.f,0.f,0.f,0.f,0.f,0.f};
    int j = j0;
    for (; j + 3 < j1; j += 4){
        int2 e0 = edge[j], e1 = edge[j+1], e2 = edge[j+2], e3 = edge[j+3];
        bf16x8 v0 = *(const bf16x8*)(h + (size_t)e0.x*128 + l*8);
        bf16x8 v1 = *(const bf16x8*)(h + (size_t)e1.x*128 + l*8);
        bf16x8 v2 = *(const bf16x8*)(h + (size_t)e2.x*128 + l*8);
        bf16x8 v3 = *(const bf16x8*)(h + (size_t)e3.x*128 + l*8);
        float w0 = __int_as_float(e0.y), w1 = __int_as_float(e1.y);
        float w2 = __int_as_float(e2.y), w3 = __int_as_float(e3.y);
        #pragma unroll
        for (int c = 0; c < 8; ++c){
            acc[c] = fmaf(bf2f(v0[c]), w0, acc[c]);
            acc[c] = fmaf(bf2f(v1[c]), w1, acc[c]);
            acc[c] = fmaf(bf2f(v2[c]), w2, acc[c]);
            acc[c] = fmaf(bf2f(v3[c]), w3, acc[c]);
        }
    }
    for (; j < j1; ++j){
        int2 e0 = edge[j];
        bf16x8 v0 = *(const bf16x8*)(h + (size_t)e0.x*128 + l*8);
        float w0 = __int_as_float(e0.y);
        #pragma unroll
        for (int c = 0; c < 8; ++c)
            acc[c] = fmaf(bf2f(v0[c]), w0, acc[c]);
    }
    bf16x8 o;
    #pragma unroll
    for (int c = 0; c < 8; ++c)
        o[c] = (short)f2bf(acc[c]);
    *(bf16x8*)(aggB + (size_t)n*128 + l*8) = o;
}

// ---- pool partial pre-reduction ----
__global__ __launch_bounds__(256) void k_attn_pre(const float* __restrict__ part, int nblk,
                                                  float* __restrict__ part2){
    __shared__ float sS[2][128], sM[2][128];
    int c = threadIdx.x & 127, g = threadIdx.x >> 7;
    float s = 0.f, m = -3.4e38f;
    for (int b = blockIdx.x*2 + g; b < nblk; b += NRED*2){
        s += part[b*128 + c];
        m = fmaxf(m, part[PMAX + b*128 + c]);
    }
    sS[g][c] = s; sM[g][c] = m;
    __syncthreads();
    if (g == 0){
        part2[blockIdx.x*128 + c] = sS[0][c] + sS[1][c];
        part2[NRED*128 + blockIdx.x*128 + c] = fmaxf(sM[0][c], sM[1][c]);
    }
}

// ---- channel attention MLP + fold att into next weights ----
// mode 0: Wdst = bf16[16384] = bf16(Wsrc * diag(att))
// mode 1: Wdst = f32[384]   = Wsrc * diag(att)
__global__ __launch_bounds__(512) void k_attn(const float* __restrict__ part2,
                       const float* __restrict__ w1, const float* __restrict__ w2,
                       const float* __restrict__ Wsrc, void* __restrict__ Wdst, int mode){
    __shared__ float sAll[4][128], mAll[4][128];
    __shared__ float avg[128], mx[128], ha[8], hm[8], attL[128];
    int c = threadIdx.x & 127, g = threadIdx.x >> 7;
    float s = 0.f, m = -3.4e38f;
    #pragma unroll
    for (int b = 0; b < NRED/4; ++b){
        int r = b*4 + g;
        s += part2[r*128 + c];
        m = fmaxf(m, part2[NRED*128 + r*128 + c]);
    }
    sAll[g][c] = s; mAll[g][c] = m;
    __syncthreads();
    if (g == 0){
        s = sAll[0][c] + sAll[1][c] + sAll[2][c] + sAll[3][c];
        m = fmaxf(fmaxf(mAll[0][c], mAll[1][c]), fmaxf(mAll[2][c], mAll[3][c]));
        avg[c] = s / (float)NN;
        mx[c] = m;
    }
    __syncthreads();
    if (threadIdx.x < 8){
        int cc = threadIdx.x;
        float sa = 0.f, sm = 0.f;
        for (int k = 0; k < 128; ++k){
            float w = w1[cc*128 + k];
            sa += avg[k]*w; sm += mx[k]*w;
        }
        ha[cc] = fmaxf(sa, 0.f); hm[cc] = fmaxf(sm, 0.f);
    }
    __syncthreads();
    if (threadIdx.x < 128){
        float oa = 0.f, om = 0.f;
        for (int j = 0; j < 8; ++j){
            float w = w2[c*8 + j];
            oa += ha[j]*w; om += hm[j]*w;
        }
        attL[c] = 1.f / (1.f + __expf(-(oa + om)));
    }
    __syncthreads();
    if (mode == 0){
        ushort* wd = (ushort*)Wdst;
        for (int i = threadIdx.x; i < 16384; i += 512)
            wd[i] = f2bf(Wsrc[i] * attL[i & 127]);
    } else {
        float* wd = (float*)Wdst;
        if (threadIdx.x < 384)
            wd[threadIdx.x] = Wsrc[threadIdx.x] * attL[threadIdx.x & 127];
    }
}

// ======== MFMA GEMM: h = ELU(aggB @ Wb^T + b) + fused pool; h stored bf16 ========
__global__ __launch_bounds__(256) void k_gemm_mfma(const ushort* __restrict__ aggB,
                        const ushort* __restrict__ Wb, const float* __restrict__ b,
                        ushort* __restrict__ h, float* __restrict__ part){
    __shared__ float poolS[4][128], poolM[4][128];
    int tid = threadIdx.x;
    int wave = tid >> 6, l = tid & 63;
    int lr = l & 15, lk = l >> 4;
    int n0 = blockIdx.x * 64 + wave * 16;

    bf16x8 a[4];
    const ushort* arow = aggB + (size_t)(n0 + lr) * 128 + lk * 8;
    #pragma unroll
    for (int kb = 0; kb < 4; ++kb)
        a[kb] = *(const bf16x8*)(arow + kb * 32);

    float s_part[8], m_part[8];
    const ushort* wbase = Wb + (size_t)lr * 128 + lk * 8;
    #pragma unroll
    for (int t = 0; t < 8; ++t){
        int j0 = t * 16;
        float bias = b[j0 + lr];
        f32x4 acc = {bias, bias, bias, bias};
        const ushort* wrow = wbase + (size_t)j0 * 128;
        #pragma unroll
        for (int kb = 0; kb < 4; ++kb){
            bf16x8 bf = *(const bf16x8*)(wrow + kb * 32);
            acc = __builtin_amdgcn_mfma_f32_16x16x32_bf16(a[kb], bf, acc, 0, 0, 0);
        }
        float s = 0.f, m = -3.4e38f;
        #pragma unroll
        for (int r = 0; r < 4; ++r){
            int n = n0 + lk * 4 + r;
            float v = elu_f(acc[r]);
            if (n < NN){
                h[(size_t)n * 128 + j0 + lr] = f2bf(v);
                s += v; m = fmaxf(m, v);
            }
        }
        s += __shfl_xor(s, 16); s += __shfl_xor(s, 32);
        m = fmaxf(m, __shfl_xor(m, 16)); m = fmaxf(m, __shfl_xor(m, 32));
        s_part[t] = s; m_part[t] = m;
    }
    if (lk == 0){
        #pragma unroll
        for (int t = 0; t < 8; ++t){
            poolS[wave][t * 16 + lr] = s_part[t];
            poolM[wave][t * 16 + lr] = m_part[t];
        }
    }
    __syncthreads();
    if (tid < 128){
        float S = poolS[0][tid] + poolS[1][tid] + poolS[2][tid] + poolS[3][tid];
        float M = fmaxf(fmaxf(poolM[0][tid], poolM[1][tid]), fmaxf(poolM[2][tid], poolM[3][tid]));
        part[blockIdx.x * 128 + tid] = S;
        part[PMAX + blockIdx.x * 128 + tid] = M;
    }
}

// ---- output head: thread per node, att3 pre-folded into WoS ----
__global__ __launch_bounds__(256) void k_out(const ushort* __restrict__ h,
                      const float* __restrict__ WoS, const float* __restrict__ bo,
                      float* __restrict__ out){
    int n = blockIdx.x * blockDim.x + threadIdx.x;
    if (n >= NN) return;
    float acc0 = bo[0], acc1 = bo[1], acc2 = bo[2];
    const bf16x8* hv = (const bf16x8*)(h + (size_t)n*128);
    #pragma unroll
    for (int i = 0; i < 16; ++i){
        bf16x8 v = hv[i];
        #pragma unroll
        for (int c = 0; c < 8; ++c){
            int cc = i*8 + c;
            float hv_f = bf2f(v[c]);
            acc0 = fmaf(hv_f, WoS[cc],        acc0);
            acc1 = fmaf(hv_f, WoS[128 + cc],  acc1);
            acc2 = fmaf(hv_f, WoS[256 + cc],  acc2);
        }
    }
    out[n*3+0] = acc0; out[n*3+1] = acc1; out[n*3+2] = acc2;
}

extern "C" void kernel_launch(void* const* d_in, const int* in_sizes, int n_in,
                              void* d_out, int out_size, void* d_ws, size_t ws_size,
                              hipStream_t stream) {
    const float* x    = (const float*)d_in[0];
    const int*   ei   = (const int*)d_in[1];
    const int*   row  = ei;
    const int*   col  = ei + NE;
    const float* dis  = (const float*)d_in[2];
    const float* W1   = (const float*)d_in[3];
    const float* b1   = (const float*)d_in[4];
    const float* W2   = (const float*)d_in[5];
    const float* b2   = (const float*)d_in[6];
    const float* W3   = (const float*)d_in[7];
    const float* b3   = (const float*)d_in[8];
    const float* ca1w1= (const float*)d_in[9];
    const float* ca1w2= (const float*)d_in[10];
    const float* ca2w1= (const float*)d_in[11];
    const float* ca2w2= (const float*)d_in[12];
    const float* ca3w1= (const float*)d_in[13];
    const float* ca3w2= (const float*)d_in[14];
    const float* Wout = (const float*)d_in[15];
    const float* bout = (const float*)d_in[16];
    float* out = (float*)d_out;

    ushort* hB    = (ushort*)d_ws;                        // [NN,128] bf16 h
    ushort* aggB  = hB + (size_t)NN*128;                  // [NPAD,128] bf16
    float*  part  = (float*)(aggB + (size_t)NPAD*128);    // 2*PMAX
    float*  part2 = part + (size_t)2*PMAX;                // 2*NRED*128
    ushort* Wb2   = (ushort*)(part2 + 2*NRED*128);        // bf16[16384], att1-scaled W2
    ushort* Wb3   = Wb2 + 16384;                          // bf16[16384], att2-scaled W3
    float*  WoutS = (float*)(Wb3 + 16384);                // f32[384], att3-scaled Wout
    int2*   edge  = (int2*)(WoutS + 384);                 // [NE]
    int*    rowptr= (int*)(edge + NE);                    // [NN+1]
    int*    hist  = rowptr + NN + 1;                      // [LT]
    int*    scanned = hist + LT;                          // [LT]
    int*    bucketPtr = scanned + LT;                     // [NBUCK+1]
    int*    bsum  = bucketPtr + NBUCK + 1;                // [NS1]
    int*    boff  = bsum + NS1;                           // [NS1]

    const int gath_blocks = (NN * 16) / 256;              // 3125

    // ---- CSR build: atomic-free two-level counting sort ----
    k_bhist<<<NBLKC, 256, 0, stream>>>(col, hist);
    k_s1<<<NS1, 256, 0, stream>>>(hist, bsum);
    k_s2<<<1, 512, 0, stream>>>(bsum, boff);
    k_s3<<<NS1, 256, 0, stream>>>(hist, boff, scanned, bucketPtr);
    k_csort<<<NBLKC, 256, 0, stream>>>(row, col, scanned, edge);
    k_dsort<<<NBUCK, 256, 0, stream>>>(dis, bucketPtr, edge, rowptr);

    // ---- layer 1 (fused gather3+dense+pool) ----
    k_l1<<<NBD3, 128, 0, stream>>>(x, rowptr, edge, W1, b1, hB, part);
    k_attn_pre<<<NRED, 256, 0, stream>>>(part, NBD3, part2);
    k_attn<<<1, 512, 0, stream>>>(part2, ca1w1, ca1w2, W2, (void*)Wb2, 0);

    // ---- layer 2 ----
    k_gather128<<<gath_blocks, 256, 0, stream>>>(hB, rowptr, edge, aggB);
    k_gemm_mfma<<<NBG, 256, 0, stream>>>(aggB, Wb2, b2, hB, part);
    k_attn_pre<<<NRED, 256, 0, stream>>>(part, NBG, part2);
    k_attn<<<1, 512, 0, stream>>>(part2, ca2w1, ca2w2, W3, (void*)Wb3, 0);

    // ---- layer 3 ----
    k_gather128<<<gath_blocks, 256, 0, stream>>>(hB, rowptr, edge, aggB);
    k_gemm_mfma<<<NBG, 256, 0, stream>>>(aggB, Wb3, b3, hB, part);
    k_attn_pre<<<NRED, 256, 0, stream>>>(part, NBG, part2);
    k_attn<<<1, 512, 0, stream>>>(part2, ca3w1, ca3w2, Wout, (void*)WoutS, 1);

    // ---- output head ----
    k_out<<<(NN+255)/256, 256, 0, stream>>>(hB, WoutS, bout, out);
}